// Round 7
// baseline (119.442 us; speedup 1.0000x reference)
//
#include <hip/hip_runtime.h>
#include <hip/hip_bf16.h>

#define NN 8192
#define DD 128

typedef short bf16x8 __attribute__((ext_vector_type(8)));
typedef float f32x4 __attribute__((ext_vector_type(4)));

#define LOG2E 1.4426950408889634f
#define K2f   14.426950408889634f   /* 10 * log2(e) */

// ws layout: packed bf16 P (chunk-major: plane c holds 16B chunk c of every
// row, P[(c*NN + row)*8 shorts]) | M | labf | G | cnt | Eg | Elg
#define M_OFF    (NN * DD * 2)
#define LABF_OFF (M_OFF + NN * 4)
#define G_OFF    (LABF_OFF + NN * 4)     /* 256 floats: [g1(128) | gtot(128)] */
#define CNT_OFF  (G_OFF + 256 * 4)
#define EG_OFF   (CNT_OFF + 256)
#define ELG_OFF  (EG_OFF + NN * 4)

__device__ __forceinline__ unsigned short f2bf(float x) {
    unsigned u = __float_as_uint(x);
    u = (u + 0x7FFFu + ((u >> 16) & 1u)) >> 16;   // RNE to bf16
    return (unsigned short)u;
}

// 256 blocks x 256 threads; 32 rows/block: fp32 -> packed bf16 (chunk-major),
// m_i, labf, class sums G, label-1 count; zeroes this block's Eg/Elg slice.
__global__ __launch_bounds__(256) void prep_kernel(const float* __restrict__ F,
        const int* __restrict__ labels, unsigned short* __restrict__ P,
        float* __restrict__ M, float* __restrict__ labf, float* __restrict__ G,
        int* __restrict__ cnt1, float* __restrict__ Eg, float* __restrict__ Elg) {
    __shared__ float sG[256];
    __shared__ int scnt;
    const int tid = threadIdx.x;
    sG[tid] = 0.f;
    if (tid == 0) scnt = 0;
    __syncthreads();
    const int wave = tid >> 6, lane = tid & 63;
    const int half = lane >> 5, l32 = lane & 31;   // half-wave per row
    const int rb = blockIdx.x * 32;
    if (tid < 32) { Eg[rb + tid] = 0.f; Elg[rb + tid] = 0.f; }
    int mycnt = 0;
    float g1a[4] = {0.f, 0.f, 0.f, 0.f}, gta[4] = {0.f, 0.f, 0.f, 0.f};
    const int ch = l32 >> 1, hh = l32 & 1;   // chunk / half-chunk for packed store
    #pragma unroll
    for (int it = 0; it < 4; ++it) {
        const int row = rb + it * 8 + wave * 2 + half;
        const int lab = labels[row];
        const float lf = (float)lab;
        const float4 f = *reinterpret_cast<const float4*>(F + row * DD + l32 * 4);
        ushort4 u;
        u.x = f2bf(f.x); u.y = f2bf(f.y); u.z = f2bf(f.z); u.w = f2bf(f.w);
        *reinterpret_cast<ushort4*>(P + ((size_t)ch * NN + row) * 8 + hh * 4) = u;
        g1a[0] = fmaf(lf, f.x, g1a[0]); gta[0] += f.x;
        g1a[1] = fmaf(lf, f.y, g1a[1]); gta[1] += f.y;
        g1a[2] = fmaf(lf, f.z, g1a[2]); gta[2] += f.z;
        g1a[3] = fmaf(lf, f.w, g1a[3]); gta[3] += f.w;
        float ss = fmaf(f.x, f.x, fmaf(f.y, f.y, fmaf(f.z, f.z, f.w * f.w)));
        #pragma unroll
        for (int off = 1; off < 32; off <<= 1) ss += __shfl_xor(ss, off);
        if (l32 == 0) {
            M[row] = 10.0f * ss;
            labf[row] = lf;
            mycnt += lab;
        }
    }
    #pragma unroll
    for (int j = 0; j < 4; ++j) {
        atomicAdd(&sG[l32 * 4 + j], g1a[j]);
        atomicAdd(&sG[128 + l32 * 4 + j], gta[j]);
    }
    if (l32 == 0 && mycnt) atomicAdd(&scnt, mycnt);
    __syncthreads();
    atomicAdd(&G[tid], sG[tid]);
    if (tid == 0) atomicAdd(cnt1, scnt);
}

// 256 blocks (16 row-groups x 16 col-groups) x 512 threads, 8 waves.
// Wave owns 64 rows (4 m-tiles, A held in regs) x 512 cols (32 iters x 16).
// No LDS/barriers; each 4KB B-fragment load now feeds 16 MFMAs (vs 8 in R6),
// halving total fragment traffic 512MB -> 256MB — the invariant that pinned
// R3-R6 at ~37us. 2 waves/SIMD (~175 VGPR), hidden by 2x per-iter work.
__global__ __launch_bounds__(512, 2) void loss_kernel(
        const unsigned short* __restrict__ P, const float* __restrict__ M,
        const float* __restrict__ labf, float* __restrict__ Eg,
        float* __restrict__ Elg) {
    const int tid  = threadIdx.x;
    const int wave = tid >> 6, lane = tid & 63;
    const int quad = lane >> 4, l16 = lane & 15;
    const int rb = (blockIdx.x & 15) * 512;
    const int cb = (blockIdx.x >> 4) * 512;
    const int rw = rb + wave * 64;

    // A fragments: plane kb*4+quad, rows rw + m*16 + l16 (coalesced 256B runs)
    bf16x8 a[4][4];
    #pragma unroll
    for (int m = 0; m < 4; m++)
        #pragma unroll
        for (int kb = 0; kb < 4; kb++)
            a[m][kb] = *reinterpret_cast<const bf16x8*>(
                P + ((size_t)(kb * 4 + quad) * NN + rw + m * 16 + l16) * 8);

    float mneg[4][4];
    #pragma unroll
    for (int m = 0; m < 4; m++)
        #pragma unroll
        for (int r = 0; r < 4; r++)
            mneg[m][r] = -M[rw + m * 16 + quad * 4 + r] * LOG2E;

    const unsigned short* pB = P + ((size_t)quad * NN + cb + l16) * 8;
    const float* pL = labf + cb + l16;

    bf16x8 bb[2][4];
    #pragma unroll
    for (int kb = 0; kb < 4; kb++)
        bb[0][kb] = *reinterpret_cast<const bf16x8*>(pB + (size_t)kb * 4 * NN * 8);
    float lcur = pL[0];

    float accE[4][4] = {}, accEl[4][4] = {};

    #pragma unroll 2
    for (int it = 0; it < 32; ++it) {
        const int cur = it & 1, nxt = cur ^ 1;
        const int itn = (it + 1) & 31;   // wrap: final prefetch harmless
        #pragma unroll
        for (int kb = 0; kb < 4; kb++)
            bb[nxt][kb] = *reinterpret_cast<const bf16x8*>(
                pB + (size_t)kb * 4 * NN * 8 + itn * 128);
        const float lnxt = pL[itn * 16];

        f32x4 d[4];
        #pragma unroll
        for (int m = 0; m < 4; m++) d[m] = f32x4{0.f, 0.f, 0.f, 0.f};
        #pragma unroll
        for (int kb = 0; kb < 4; kb++)
            #pragma unroll
            for (int m = 0; m < 4; m++)
                d[m] = __builtin_amdgcn_mfma_f32_16x16x32_bf16(
                    a[m][kb], bb[cur][kb], d[m], 0, 0, 0);

        #pragma unroll
        for (int m = 0; m < 4; m++) {
            #pragma unroll
            for (int r = 0; r < 4; r++) {
                const float e = exp2f(fmaf(d[m][r], K2f, mneg[m][r]));
                accE[m][r] += e;
                accEl[m][r] = fmaf(lcur, e, accEl[m][r]);
            }
        }
        lcur = lnxt;
    }

    // 16-lane row reduce, then one global atomic per (row, stat)
    #pragma unroll
    for (int m = 0; m < 4; m++) {
        #pragma unroll
        for (int r = 0; r < 4; r++) {
            float e = accE[m][r], el = accEl[m][r];
            #pragma unroll
            for (int off = 1; off < 16; off <<= 1) {
                e  += __shfl_xor(e,  off);
                el += __shfl_xor(el, off);
            }
            if (l16 == 0) {
                const int row = rw + m * 16 + quad * 4 + r;
                atomicAdd(&Eg[row], e);
                atomicAdd(&Elg[row], el);
            }
        }
    }
}

// 32 blocks x 256 threads: per-row finalize (fp32 class-sum dot + log terms)
__global__ __launch_bounds__(256) void final_kernel(
        const float* __restrict__ F, const float* __restrict__ M,
        const int* __restrict__ labels, const float* __restrict__ G,
        const int* __restrict__ cnt1, const float* __restrict__ Eg,
        const float* __restrict__ Elg, float* __restrict__ out) {
    __shared__ float sG[256];
    __shared__ float wsum[4];
    const int tid = threadIdx.x;
    sG[tid] = G[tid];
    __syncthreads();
    const int row = blockIdx.x * 256 + tid;
    const int lr = labels[row];
    float dot = 0.f;
    const float* f = F + (size_t)row * DD;
    #pragma unroll
    for (int k = 0; k < DD; k += 4) {
        const float4 fv = *reinterpret_cast<const float4*>(f + k);
        #pragma unroll
        for (int j = 0; j < 4; j++) {
            const float fj = (&fv.x)[j];
            const float g1 = sG[k + j];
            const float gl = lr ? g1 : (sG[128 + k + j] - g1);
            dot = fmaf(fj, gl, dot);
        }
    }
    const float E    = Eg[row];
    const float El   = Elg[row];
    const float Epos = lr ? El : (E - El);     // pos exp-sum (incl diag)
    const float Si   = E - Epos;               // neg exp-sum
    const float mi   = M[row];
    const int   c1   = *cnt1;
    const float cntp1 = (float)(lr ? c1 : (NN - c1));
    const float cnt   = cntp1 - 1.f;
    const float sum_l   = fmaf(10.f, dot, -cntp1 * mi);
    const float sum_log = cntp1 * __logf(Si) + Epos / Si;
    float li = -(10.f / 7.f) * (sum_l - sum_log) / cnt;
    #pragma unroll
    for (int off = 1; off < 64; off <<= 1) li += __shfl_xor(li, off);
    if ((tid & 63) == 0) wsum[tid >> 6] = li;
    __syncthreads();
    if (tid == 0)
        atomicAdd(out, (wsum[0] + wsum[1] + wsum[2] + wsum[3]) * (1.0f / NN));
}

extern "C" void kernel_launch(void* const* d_in, const int* in_sizes, int n_in,
                              void* d_out, int out_size, void* d_ws, size_t ws_size,
                              hipStream_t stream) {
    const float* F      = (const float*)d_in[0];
    const int*   labels = (const int*)d_in[1];
    float*       out    = (float*)d_out;
    char*        ws     = (char*)d_ws;
    unsigned short* P   = (unsigned short*)ws;
    float*       M      = (float*)(ws + M_OFF);
    float*       labf   = (float*)(ws + LABF_OFF);
    float*       G      = (float*)(ws + G_OFF);
    int*         cnt1   = (int*)(ws + CNT_OFF);
    float*       Eg     = (float*)(ws + EG_OFF);
    float*       Elg    = (float*)(ws + ELG_OFF);

    hipMemsetAsync(out, 0, sizeof(float), stream);
    hipMemsetAsync(ws + G_OFF, 0, 256 * 4 + 256, stream);  // G + cnt1

    prep_kernel<<<NN / 32, 256, 0, stream>>>(F, labels, P, M, labf, G, cnt1, Eg, Elg);
    loss_kernel<<<256, 512, 0, stream>>>(P, M, labf, Eg, Elg);
    final_kernel<<<NN / 256, 256, 0, stream>>>(F, M, labels, G, cnt1, Eg, Elg, out);
}

// Round 8
// 108.616 us; speedup vs baseline: 1.0997x; 1.0997x over previous
//
#include <hip/hip_runtime.h>
#include <hip/hip_bf16.h>

#define NN 8192
#define DD 128

typedef short bf16x8 __attribute__((ext_vector_type(8)));
typedef float f32x4 __attribute__((ext_vector_type(4)));

#define LOG2E 1.4426950408889634f
#define K2f   14.426950408889634f   /* 10 * log2(e) */

// ws layout: packed bf16 P (chunk-major) | M | labf | G | cnt | Eg | Elg | TEg | TElg
#define M_OFF    (NN * DD * 2)
#define LABF_OFF (M_OFF + NN * 4)
#define G_OFF    (LABF_OFF + NN * 4)     /* 256 floats: [g1(128) | gtot(128)] */
#define CNT_OFF  (G_OFF + 256 * 4)
#define EG_OFF   (CNT_OFF + 256)
#define ELG_OFF  (EG_OFF + NN * 4)
#define TEG_OFF  (ELG_OFF + NN * 4)
#define TELG_OFF (TEG_OFF + NN * 4)

__device__ __forceinline__ unsigned short f2bf(float x) {
    unsigned u = __float_as_uint(x);
    u = (u + 0x7FFFu + ((u >> 16) & 1u)) >> 16;   // RNE to bf16
    return (unsigned short)u;
}

// 256 blocks x 256 threads; 32 rows/block: fp32 -> packed bf16 (chunk-major),
// m_i, labf, class sums G, count; zeroes this block's Eg/Elg/TEg/TElg slices.
__global__ __launch_bounds__(256) void prep_kernel(const float* __restrict__ F,
        const int* __restrict__ labels, unsigned short* __restrict__ P,
        float* __restrict__ M, float* __restrict__ labf, float* __restrict__ G,
        int* __restrict__ cnt1, float* __restrict__ Eg, float* __restrict__ Elg,
        float* __restrict__ TEg, float* __restrict__ TElg) {
    __shared__ float sG[256];
    __shared__ int scnt;
    const int tid = threadIdx.x;
    sG[tid] = 0.f;
    if (tid == 0) scnt = 0;
    __syncthreads();
    const int wave = tid >> 6, lane = tid & 63;
    const int half = lane >> 5, l32 = lane & 31;   // half-wave per row
    const int rb = blockIdx.x * 32;
    if (tid < 32) {
        Eg[rb + tid] = 0.f; Elg[rb + tid] = 0.f;
        TEg[rb + tid] = 0.f; TElg[rb + tid] = 0.f;
    }
    int mycnt = 0;
    float g1a[4] = {0.f, 0.f, 0.f, 0.f}, gta[4] = {0.f, 0.f, 0.f, 0.f};
    const int ch = l32 >> 1, hh = l32 & 1;
    #pragma unroll
    for (int it = 0; it < 4; ++it) {
        const int row = rb + it * 8 + wave * 2 + half;
        const int lab = labels[row];
        const float lf = (float)lab;
        const float4 f = *reinterpret_cast<const float4*>(F + row * DD + l32 * 4);
        ushort4 u;
        u.x = f2bf(f.x); u.y = f2bf(f.y); u.z = f2bf(f.z); u.w = f2bf(f.w);
        *reinterpret_cast<ushort4*>(P + ((size_t)ch * NN + row) * 8 + hh * 4) = u;
        g1a[0] = fmaf(lf, f.x, g1a[0]); gta[0] += f.x;
        g1a[1] = fmaf(lf, f.y, g1a[1]); gta[1] += f.y;
        g1a[2] = fmaf(lf, f.z, g1a[2]); gta[2] += f.z;
        g1a[3] = fmaf(lf, f.w, g1a[3]); gta[3] += f.w;
        float ss = fmaf(f.x, f.x, fmaf(f.y, f.y, fmaf(f.z, f.z, f.w * f.w)));
        #pragma unroll
        for (int off = 1; off < 32; off <<= 1) ss += __shfl_xor(ss, off);
        if (l32 == 0) {
            M[row] = 10.0f * ss;
            labf[row] = lf;
            mycnt += lab;
        }
    }
    #pragma unroll
    for (int j = 0; j < 4; ++j) {
        atomicAdd(&sG[l32 * 4 + j], g1a[j]);
        atomicAdd(&sG[128 + l32 * 4 + j], gta[j]);
    }
    if (l32 == 0 && mycnt) atomicAdd(&scnt, mycnt);
    __syncthreads();
    atomicAdd(&G[tid], sG[tid]);
    if (tid == 0) atomicAdd(cnt1, scnt);
}

// Symmetric-triangle Gram: 528 blocks (rg<=cg over 32x32 grid of 256x256
// tiles) x 512 threads. Wave owns 32 rows x 256 cols (16 iters x 16). Each
// off-diag tile also produces TRANSPOSED stats for its 256 cols via
// e_ji = [e_ij * w_i] * exp(10-m_j): per-lane col-sums (D-frag col = lane&15
// for all 8 elems), quad-shfl reduce, LDS atomic, block flush to TEg/TElg.
// Work (MFMA/exp/fragment traffic) = 52% of the R6 full-matrix version.
__global__ __launch_bounds__(512, 4) void loss_kernel(
        const unsigned short* __restrict__ P, const float* __restrict__ M,
        const float* __restrict__ labf, float* __restrict__ Eg,
        float* __restrict__ Elg, float* __restrict__ TEg,
        float* __restrict__ TElg) {
    __shared__ float colE[256], colEl[256];
    const int tid  = threadIdx.x;
    const int wave = tid >> 6, lane = tid & 63;
    const int quad = lane >> 4, l16 = lane & 15;

    // triangle decode (uniform)
    int b = blockIdx.x, rg = 0;
    while (b >= 32 - rg) { b -= 32 - rg; rg++; }
    const int cg = rg + b;
    const bool diag = (b == 0);
    const int rb = rg * 256, cb = cg * 256;
    const int rw = rb + wave * 32;

    if (tid < 256) colE[tid] = 0.f; else colEl[tid - 256] = 0.f;

    // A fragments: plane kb*4+quad, rows rw+m*16+l16 (coalesced 256B runs)
    bf16x8 a[2][4];
    #pragma unroll
    for (int m = 0; m < 2; m++)
        #pragma unroll
        for (int kb = 0; kb < 4; kb++)
            a[m][kb] = *reinterpret_cast<const bf16x8*>(
                P + ((size_t)(kb * 4 + quad) * NN + rw + m * 16 + l16) * 8);

    // row invariants (D-frag row = m*16 + quad*4 + r)
    float mneg[2][4], w[2][4], lw[2][4];
    #pragma unroll
    for (int m = 0; m < 2; m++)
        #pragma unroll
        for (int r = 0; r < 4; r++) {
            const int row = rw + m * 16 + quad * 4 + r;
            const float mi = M[row];
            mneg[m][r] = -mi * LOG2E;
            w[m][r] = exp2f((mi - 10.f) * LOG2E);   // exp(m_i - 10)
            lw[m][r] = labf[row] * w[m][r];
        }

    const unsigned short* pB = P + ((size_t)quad * NN + cb + l16) * 8;
    const float* pL = labf + cb + l16;

    bf16x8 bb[2][4];
    #pragma unroll
    for (int kb = 0; kb < 4; kb++)
        bb[0][kb] = *reinterpret_cast<const bf16x8*>(pB + (size_t)kb * 4 * NN * 8);
    float lcur = pL[0];

    float accE[2][4] = {}, accEl[2][4] = {};
    __syncthreads();   // covers colE/colEl init

    #pragma unroll 2
    for (int it = 0; it < 16; ++it) {
        const int cur = it & 1, nxt = cur ^ 1;
        const int itn = (it + 1) & 15;   // wrap: final prefetch harmless
        #pragma unroll
        for (int kb = 0; kb < 4; kb++)
            bb[nxt][kb] = *reinterpret_cast<const bf16x8*>(
                pB + (size_t)kb * 4 * NN * 8 + itn * 128);
        const float lnxt = pL[itn * 16];

        f32x4 d0 = {0.f, 0.f, 0.f, 0.f}, d1 = {0.f, 0.f, 0.f, 0.f};
        #pragma unroll
        for (int kb = 0; kb < 4; kb++) {
            d0 = __builtin_amdgcn_mfma_f32_16x16x32_bf16(a[0][kb], bb[cur][kb], d0, 0, 0, 0);
            d1 = __builtin_amdgcn_mfma_f32_16x16x32_bf16(a[1][kb], bb[cur][kb], d1, 0, 0, 0);
        }

        float cE = 0.f, cEl = 0.f;
        #pragma unroll
        for (int m = 0; m < 2; m++) {
            #pragma unroll
            for (int r = 0; r < 4; r++) {
                const float vv = (m == 0) ? d0[r] : d1[r];
                const float e = exp2f(fmaf(vv, K2f, mneg[m][r]));
                accE[m][r] += e;
                accEl[m][r] = fmaf(lcur, e, accEl[m][r]);
                cE  = fmaf(w[m][r],  e, cE);
                cEl = fmaf(lw[m][r], e, cEl);
            }
        }
        if (!diag) {
            // reduce over quads (the wave's 32 rows); col = l16
            cE  += __shfl_xor(cE, 16);  cE  += __shfl_xor(cE, 32);
            cEl += __shfl_xor(cEl, 16); cEl += __shfl_xor(cEl, 32);
            if (quad == 0) {
                atomicAdd(&colE[it * 16 + l16], cE);
                atomicAdd(&colEl[it * 16 + l16], cEl);
            }
        }
        lcur = lnxt;
    }

    // row stats: 16-lane reduce, one global atomic per (row, stat)
    #pragma unroll
    for (int m = 0; m < 2; m++) {
        #pragma unroll
        for (int r = 0; r < 4; r++) {
            float e = accE[m][r], el = accEl[m][r];
            #pragma unroll
            for (int off = 1; off < 16; off <<= 1) {
                e  += __shfl_xor(e,  off);
                el += __shfl_xor(el, off);
            }
            if (l16 == 0) {
                const int row = rw + m * 16 + quad * 4 + r;
                atomicAdd(&Eg[row], e);
                atomicAdd(&Elg[row], el);
            }
        }
    }

    if (!diag) {
        __syncthreads();
        if (tid < 256) atomicAdd(&TEg[cb + tid], colE[tid]);
        else           atomicAdd(&TElg[cb + tid - 256], colEl[tid - 256]);
    }
}

// 32 blocks x 256 threads: per-row finalize (fp32 class-sum dot + log terms)
__global__ __launch_bounds__(256) void final_kernel(
        const float* __restrict__ F, const float* __restrict__ M,
        const int* __restrict__ labels, const float* __restrict__ G,
        const int* __restrict__ cnt1, const float* __restrict__ Eg,
        const float* __restrict__ Elg, const float* __restrict__ TEg,
        const float* __restrict__ TElg, float* __restrict__ out) {
    __shared__ float sG[256];
    __shared__ float wsum[4];
    const int tid = threadIdx.x;
    sG[tid] = G[tid];
    __syncthreads();
    const int row = blockIdx.x * 256 + tid;
    const int lr = labels[row];
    float dot = 0.f;
    const float* f = F + (size_t)row * DD;
    #pragma unroll
    for (int k = 0; k < DD; k += 4) {
        const float4 fv = *reinterpret_cast<const float4*>(f + k);
        #pragma unroll
        for (int j = 0; j < 4; j++) {
            const float fj = (&fv.x)[j];
            const float g1 = sG[k + j];
            const float gl = lr ? g1 : (sG[128 + k + j] - g1);
            dot = fmaf(fj, gl, dot);
        }
    }
    const float mi = M[row];
    const float tf = exp2f((10.f - mi) * LOG2E);   // exp(10 - m_j)
    const float E    = Eg[row]  + tf * TEg[row];
    const float El   = Elg[row] + tf * TElg[row];
    const float Epos = lr ? El : (E - El);     // pos exp-sum (incl diag)
    const float Si   = E - Epos;               // neg exp-sum
    const int   c1   = *cnt1;
    const float cntp1 = (float)(lr ? c1 : (NN - c1));
    const float cnt   = cntp1 - 1.f;
    const float sum_l   = fmaf(10.f, dot, -cntp1 * mi);
    const float sum_log = cntp1 * __logf(Si) + Epos / Si;
    float li = -(10.f / 7.f) * (sum_l - sum_log) / cnt;
    #pragma unroll
    for (int off = 1; off < 64; off <<= 1) li += __shfl_xor(li, off);
    if ((tid & 63) == 0) wsum[tid >> 6] = li;
    __syncthreads();
    if (tid == 0)
        atomicAdd(out, (wsum[0] + wsum[1] + wsum[2] + wsum[3]) * (1.0f / NN));
}

extern "C" void kernel_launch(void* const* d_in, const int* in_sizes, int n_in,
                              void* d_out, int out_size, void* d_ws, size_t ws_size,
                              hipStream_t stream) {
    const float* F      = (const float*)d_in[0];
    const int*   labels = (const int*)d_in[1];
    float*       out    = (float*)d_out;
    char*        ws     = (char*)d_ws;
    unsigned short* P   = (unsigned short*)ws;
    float*       M      = (float*)(ws + M_OFF);
    float*       labf   = (float*)(ws + LABF_OFF);
    float*       G      = (float*)(ws + G_OFF);
    int*         cnt1   = (int*)(ws + CNT_OFF);
    float*       Eg     = (float*)(ws + EG_OFF);
    float*       Elg    = (float*)(ws + ELG_OFF);
    float*       TEg    = (float*)(ws + TEG_OFF);
    float*       TElg   = (float*)(ws + TELG_OFF);

    hipMemsetAsync(out, 0, sizeof(float), stream);
    hipMemsetAsync(ws + G_OFF, 0, 256 * 4 + 256, stream);  // G + cnt1

    prep_kernel<<<NN / 32, 256, 0, stream>>>(F, labels, P, M, labf, G, cnt1,
                                             Eg, Elg, TEg, TElg);
    loss_kernel<<<528, 512, 0, stream>>>(P, M, labf, Eg, Elg, TEg, TElg);
    final_kernel<<<NN / 256, 256, 0, stream>>>(F, M, labels, G, cnt1,
                                               Eg, Elg, TEg, TElg, out);
}